// Round 4
// baseline (328.730 us; speedup 1.0000x reference)
//
#include <hip/hip_runtime.h>
#include <hip/hip_fp16.h>
#include <math.h>

#define BATCH 16
#define CIN   128
#define LIN   8192
#define COUT  128
#define LOUT  16384
#define KEXP  768          // 2 shift-halves * (3 powers * 128 channels)
#define NT    256          // i-tile width (big: weight-stream reuse across 128 cols/wave)
#define NTILES (LIN/NT)    // 32
#define PCOLS 258          // i0-1 .. i0+256 inclusive
#define PCPAD 136          // halfwords per col; 272B stride, 16B aligned
#define PSZ   (PCOLS*PCPAD)  // one plane: 35088 halfwords = 70176 B

typedef _Float16 f16x8 __attribute__((ext_vector_type(8)));
typedef float    f32x4 __attribute__((ext_vector_type(4)));

// ---------------- weight prep: fold taps, cast fp16, PHASE-MAJOR frag swizzle ----------------
__global__ void prep_weights(const float* __restrict__ W,
                             _Float16* __restrict__ WE,
                             _Float16* __restrict__ WO) {
  int idx = blockIdx.x * 256 + threadIdx.x;       // 128*768 total
  int co = idx / KEXP;
  int k  = idx % KEXP;
  int sh = (k >= 384) ? 1 : 0;
  int cq = k - 384 * sh;                          // 384 is NOT a power of two
  const float* w = W + ((size_t)co * 384 + cq) * 3;
  float we, wo;
  if (sh == 0) { we = w[0];        wo = w[0] + w[1]; }
  else         { we = w[1] + w[2]; wo = w[2];        }
  int q  = cq >> 7;            // power plane 0..2
  int c  = cq & 127;           // channel within plane
  int ks = q * 8 + sh * 4 + (c >> 5);
  int kk = c & 31, quad = kk >> 3, j = kk & 7;
  int mtile = co >> 4, l15 = co & 15;
  size_t off = ((size_t)((mtile * 24 + ks) * 64) + quad * 16 + l15) * 8 + j;
  WE[off] = (_Float16)we;
  WO[off] = (_Float16)wo;
}

// ---------------- fused conv GEMM ----------------
// v5: NT=256, 512 threads = 8 waves (2wm x 2wn x E/O), 128 cols/wave.
//  - weight L2 traffic = const/colsPerWave -> 0.39 GB (v4's 32-col split = 1.57 GB
//    = 108K cyc/CU L2 floor, the real v4 regression cause)
//  - 512 blocks -> 2 rounds/CU: half the prologue/epilogue latency exposures
//  - 2 LDS plane buffers (70KB ea): P1=x from HBM; P2=P1*P1 and P3=P2*P1 built
//    in fp16 from the resident plane, owner-computes (each thread rw its own
//    cells only -> race-free), overlapped with the s=0 MFMA burst of the phase
//  - per-ks burst = 32 MFMA (512 cyc/wave): distance-1 af/bf prefetch suffices

#define AFLOAD(DST, KS) do {                                               \
  _Pragma("unroll")                                                        \
  for (int fm = 0; fm < 4; ++fm) {                                         \
    int mt = wm * 4 + fm;                                                  \
    DST[fm] = *(const f16x8*)(Wsel + ((size_t)((mt * 24 + (KS)) * 64) + lane) * 8); \
  }                                                                        \
} while (0)

#define BFLOAD(DST, CUR, S) do {                                           \
  const _Float16* pb = (CUR) + (((S) & 3) * 32) + kl;                      \
  const int shft = (((S) >> 2) + isO);                                     \
  _Pragma("unroll")                                                        \
  for (int fn = 0; fn < 8; ++fn) {                                         \
    int colB = wn * 128 + fn * 16 + l15 + shft;                            \
    DST[fn] = *(const f16x8*)(pb + colB * PCPAD);                          \
  }                                                                        \
} while (0)

// owner-computes product plane builds (each thread touches only its own cells)
#define BUILD_P2() do {                                                    \
  _Pragma("unroll")                                                        \
  for (int slot = 0; slot < 9; ++slot) {                                   \
    if (slot < 8 || t < PCOLS * 16 - 4096) {                               \
      int task = t + 512 * slot;                                           \
      int g    = task / PCOLS;                                             \
      int col  = task - g * PCOLS;                                         \
      int off  = col * PCPAD + g * 8;                                      \
      f16x8 v = *(f16x8*)(planes + off);                                   \
      *(f16x8*)(planes + PSZ + off) = v * v;                               \
    }                                                                      \
  }                                                                        \
} while (0)

#define BUILD_P3() do {                                                    \
  _Pragma("unroll")                                                        \
  for (int slot = 0; slot < 9; ++slot) {                                   \
    if (slot < 8 || t < PCOLS * 16 - 4096) {                               \
      int task = t + 512 * slot;                                           \
      int g    = task / PCOLS;                                             \
      int col  = task - g * PCOLS;                                         \
      int off  = col * PCPAD + g * 8;                                      \
      f16x8 v1 = *(f16x8*)(planes + off);                                  \
      f16x8 v2 = *(f16x8*)(planes + PSZ + off);                            \
      *(f16x8*)(planes + off) = v1 * v2;                                   \
    }                                                                      \
  }                                                                        \
} while (0)

__launch_bounds__(512, 2)
__global__ void conv_gemm(const float* __restrict__ x,
                          const _Float16* __restrict__ WE,
                          const _Float16* __restrict__ WO,
                          float* __restrict__ out,
                          float* __restrict__ stats) {
  extern __shared__ char smem[];
  float*    sstats = (float*)smem;                 // [128][2]
  _Float16* planes = (_Float16*)(smem + 1024);     // [2][PSZ]

  const int tile = blockIdx.x;        // 0..31
  const int b    = blockIdx.y;        // 0..15
  const int i0   = tile * NT;
  const int t    = threadIdx.x;
  const int lane = t & 63;
  const int wave = t >> 6;            // 0..7
  const int isO  = wave & 1;          // 0=even outputs, 1=odd outputs
  const int wn   = (wave >> 1) & 1;   // 128-col half of the tile
  const int wm   = wave >> 2;         // 64-cout half
  const int l15  = lane & 15, quad = lane >> 4;
  const int kl   = quad * 8;

  if (t < 128) { sstats[2 * t] = 0.f; sstats[2 * t + 1] = 0.f; }

  const float* xb = x + (size_t)b * CIN * LIN;
  const _Float16* Wsel = isO ? WO : WE;

  f32x4 acc[4][8];
  const f32x4 zero = {0.f, 0.f, 0.f, 0.f};
#pragma unroll
  for (int fm = 0; fm < 4; ++fm)
#pragma unroll
    for (int fn = 0; fn < 8; ++fn) acc[fm][fn] = zero;

  f16x8 af[2][4], bf[2][8];
  AFLOAD(af[0], 0);                 // weight prefetch: global, independent of barrier

  // ---- prologue: build P1 (x, fp16) only; P2/P3 derived later in-LDS ----
#pragma unroll
  for (int slot = 0; slot < 9; ++slot) {
    const bool tval = (slot < 8) || (t < PCOLS * 16 - 4096);   // 4128 tasks
    int task = t + 512 * slot;
    int g    = task / PCOLS;                        // 8-channel group 0..15
    int col  = task - g * PCOLS;                    // consecutive t -> consecutive col
    int gi   = i0 - 1 + col;
    const bool ok = tval && gi >= 0 && gi < LIN;
    const float* px = xb + (size_t)g * 8 * LIN + gi;
    f16x8 w1;
#pragma unroll
    for (int j = 0; j < 8; ++j) {
      float v = ok ? px[(size_t)j * LIN] : 0.f;
      w1[j] = (_Float16)v;
    }
    if (tval) *(f16x8*)(planes + col * PCPAD + g * 8) = w1;
  }
  __syncthreads();

#pragma unroll
  for (int q = 0; q < 3; ++q) {
    _Float16* cur = planes + ((q == 1) ? PSZ : 0);  // q0:P1(buf0) q1:P2(buf1) q2:P3(buf0)
    BFLOAD(bf[0], cur, 0);
#pragma unroll
    for (int s = 0; s < 8; ++s) {
      const int ks = q * 8 + s;
      if (ks + 1 < 24) AFLOAD(af[(ks + 1) & 1], ks + 1);
      if (s + 1 < 8)   BFLOAD(bf[(s + 1) & 1], cur, s + 1);
      __builtin_amdgcn_s_setprio(1);
#pragma unroll
      for (int fm = 0; fm < 4; ++fm)
#pragma unroll
        for (int fn = 0; fn < 8; ++fn)
          acc[fm][fn] = __builtin_amdgcn_mfma_f32_16x16x32_f16(af[ks & 1][fm], bf[s & 1][fn], acc[fm][fn], 0, 0, 0);
      __builtin_amdgcn_s_setprio(0);
      if (s == 0 && q == 0) BUILD_P2();   // buf1 <- P1*P1, overlapped w/ 7 bursts
      if (s == 0 && q == 1) BUILD_P3();   // buf0 <- P2*P1 (own-cell rw; q1 reads buf1)
    }
    __syncthreads();   // derived plane visible; cur safe for next q
  }

  // --- epilogue: per-wave stats + direct interleave-by-wave stores ---
  // C/D layout: n = lane&15, m = quad*4 + r
  float* orow_base = out + (size_t)b * COUT * LOUT + isO;
#pragma unroll
  for (int fm = 0; fm < 4; ++fm) {
#pragma unroll
    for (int r = 0; r < 4; ++r) {
      float s1 = 0.f, s2 = 0.f;
#pragma unroll
      for (int fn = 0; fn < 8; ++fn) {
        float v = acc[fm][fn][r];
        s1 += v;
        s2 += v * v;
      }
#pragma unroll
      for (int off = 8; off >= 1; off >>= 1) {   // reduce across the 16 n-lanes
        s1 += __shfl_xor(s1, off, 64);
        s2 += __shfl_xor(s2, off, 64);
      }
      int co = wm * 64 + fm * 16 + quad * 4 + r;
      if (l15 == 0) {
        atomicAdd(&sstats[2 * co], s1);
        atomicAdd(&sstats[2 * co + 1], s2);
      }
      float* orow = orow_base + (size_t)co * LOUT;
#pragma unroll
      for (int fn = 0; fn < 8; ++fn) {
        int n = i0 + wn * 128 + fn * 16 + l15;
        orow[2 * n] = acc[fm][fn][r];            // E/O waves write complementary 4B-interleave; L2 merges
      }
    }
  }
  __syncthreads();
  if (t < 128) {
    atomicAdd(&stats[((size_t)b * COUT + t) * 2],     sstats[2 * t]);
    atomicAdd(&stats[((size_t)b * COUT + t) * 2 + 1], sstats[2 * t + 1]);
  }
}

// ---------------- instance norm + tanh, in place ----------------
__device__ inline float tanh_fast(float z) {
  float e = __expf(2.f * z);
  return 1.f - 2.f * __builtin_amdgcn_rcpf(e + 1.f);  // v_rcp_f32: no fdiv slow-path
}

__global__ void norm_tanh(float* __restrict__ out, const float* __restrict__ stats) {
  int row  = blockIdx.x >> 1;                   // b*128 + co
  int half = blockIdx.x & 1;
  float s1 = stats[2 * row], s2 = stats[2 * row + 1];
  const float invN = 1.f / (float)LOUT;
  float mean = s1 * invN;
  float var  = fmaxf(s2 * invN - mean * mean, 0.f);
  float inv  = rsqrtf(var + 1e-5f);
  float c0   = -mean * inv;
  float4* p = (float4*)(out + (size_t)row * LOUT) + half * (LOUT / 8);
  for (int i = threadIdx.x; i < LOUT / 8; i += 256) {
    float4 v = p[i];
    v.x = tanh_fast(fmaf(v.x, inv, c0));
    v.y = tanh_fast(fmaf(v.y, inv, c0));
    v.z = tanh_fast(fmaf(v.z, inv, c0));
    v.w = tanh_fast(fmaf(v.w, inv, c0));
    p[i] = v;
  }
}

extern "C" void kernel_launch(void* const* d_in, const int* in_sizes, int n_in,
                              void* d_out, int out_size, void* d_ws, size_t ws_size,
                              hipStream_t stream) {
  const float* x = (const float*)d_in[0];
  const float* W = (const float*)d_in[1];
  // bias (d_in[2]) is exactly cancelled by InstanceNorm -> unused
  float* out = (float*)d_out;

  float*    stats = (float*)d_ws;
  _Float16* WE    = (_Float16*)((char*)d_ws + 16384);
  _Float16* WO    = WE + (size_t)COUT * KEXP;

  hipMemsetAsync(d_ws, 0, 16384, stream);
  prep_weights<<<dim3((COUT * KEXP) / 256), dim3(256), 0, stream>>>(W, WE, WO);

  size_t shmem = 1024 + (size_t)PSZ * 2 * 2;   // 141,376 B -> 1 block/CU, 8 waves
  hipFuncSetAttribute(reinterpret_cast<const void*>(conv_gemm),
                      hipFuncAttributeMaxDynamicSharedMemorySize, (int)shmem);
  conv_gemm<<<dim3(NTILES, BATCH), dim3(512), shmem, stream>>>(x, WE, WO, out, stats);

  norm_tanh<<<dim3(2 * BATCH * COUT), dim3(256), 0, stream>>>(out, stats);
}

// Round 5
// 327.396 us; speedup vs baseline: 1.0041x; 1.0041x over previous
//
#include <hip/hip_runtime.h>
#include <hip/hip_fp16.h>
#include <math.h>

#define BATCH 16
#define CIN   128
#define LIN   8192
#define COUT  128
#define LOUT  16384
#define KEXP  768          // 2 shift-halves * (3 powers * 128 channels)
#define NT    256          // i-tile width (weight-stream reuse; 2 rounds/CU)
#define NTILES (LIN/NT)    // 32
#define PCOLS 258          // i0-1 .. i0+256 inclusive
#define PCPAD 136          // halfwords per col; 272B stride, 16B aligned
#define PSZ   (PCOLS*PCPAD)  // one plane: 35088 halfwords = 70176 B

typedef _Float16 f16x8 __attribute__((ext_vector_type(8)));
typedef float    f32x4 __attribute__((ext_vector_type(4)));

// ---------------- weight prep: fold taps, cast fp16, PHASE-MAJOR frag swizzle ----------------
__global__ void prep_weights(const float* __restrict__ W,
                             _Float16* __restrict__ WE,
                             _Float16* __restrict__ WO) {
  int idx = blockIdx.x * 256 + threadIdx.x;       // 128*768 total
  int co = idx / KEXP;
  int k  = idx % KEXP;
  int sh = (k >= 384) ? 1 : 0;
  int cq = k - 384 * sh;                          // 384 is NOT a power of two
  const float* w = W + ((size_t)co * 384 + cq) * 3;
  float we, wo;
  if (sh == 0) { we = w[0];        wo = w[0] + w[1]; }
  else         { we = w[1] + w[2]; wo = w[2];        }
  int q  = cq >> 7;            // power plane 0..2
  int c  = cq & 127;           // channel within plane
  int ks = q * 8 + sh * 4 + (c >> 5);
  int kk = c & 31, quad = kk >> 3, j = kk & 7;
  int mtile = co >> 4, l15 = co & 15;
  size_t off = ((size_t)((mtile * 24 + ks) * 64) + quad * 16 + l15) * 8 + j;
  WE[off] = (_Float16)we;
  WO[off] = (_Float16)wo;
}

// ---------------- fused conv GEMM ----------------
// v6: NT=256, 512 thr = 8 waves (2wm x 2wn x E/O), 128 cols/wave, 2 rounds/CU.
//  - bf HALF-RING bf[2][4]: prefetch distance = half k-step. VGPR-side = 64 bf
//    + 32 af + addr ~= 111 <= 128 cap (v5's bf[2][8]=128 blew the cap -> regalloc
//    killed the pipeline; that was the v5 regression)
//  - in-LDS power builds kept from v5 (P2=P1*P1, P3=P2*P1, owner-computes)
//  - epilogue assembles the 128x512 tile in LDS (plane region is dead) in two
//    64-row passes -> contiguous full-line f32x4 stores (fixes v5's 180MB writes)

#define AFLOAD(DST, KS) do {                                               \
  _Pragma("unroll")                                                        \
  for (int fm = 0; fm < 4; ++fm) {                                         \
    int mt = wm * 4 + fm;                                                  \
    DST[fm] = *(const f16x8*)(Wsel + ((size_t)((mt * 24 + (KS)) * 64) + lane) * 8); \
  }                                                                        \
} while (0)

// load 4 fn-frags (half H of the 8) for k-step s within plane CUR
#define BFLOAD4(DST, CUR, S, H) do {                                       \
  const _Float16* pb = (CUR) + (((S) & 3) * 32) + kl;                      \
  const int shft = (((S) >> 2) + isO);                                     \
  _Pragma("unroll")                                                        \
  for (int f4 = 0; f4 < 4; ++f4) {                                         \
    int colB = wn * 128 + ((H) * 4 + f4) * 16 + l15 + shft;                \
    DST[f4] = *(const f16x8*)(pb + colB * PCPAD);                          \
  }                                                                        \
} while (0)

// owner-computes product plane builds (each thread touches only its own cells)
#define BUILD_P2() do {                                                    \
  _Pragma("unroll")                                                        \
  for (int slot = 0; slot < 9; ++slot) {                                   \
    if (slot < 8 || t < PCOLS * 16 - 4096) {                               \
      int task = t + 512 * slot;                                           \
      int g    = task / PCOLS;                                             \
      int col  = task - g * PCOLS;                                         \
      int off  = col * PCPAD + g * 8;                                      \
      f16x8 v = *(f16x8*)(planes + off);                                   \
      *(f16x8*)(planes + PSZ + off) = v * v;                               \
    }                                                                      \
  }                                                                        \
} while (0)

#define BUILD_P3() do {                                                    \
  _Pragma("unroll")                                                        \
  for (int slot = 0; slot < 9; ++slot) {                                   \
    if (slot < 8 || t < PCOLS * 16 - 4096) {                               \
      int task = t + 512 * slot;                                           \
      int g    = task / PCOLS;                                             \
      int col  = task - g * PCOLS;                                         \
      int off  = col * PCPAD + g * 8;                                      \
      f16x8 v1 = *(f16x8*)(planes + off);                                  \
      f16x8 v2 = *(f16x8*)(planes + PSZ + off);                            \
      *(f16x8*)(planes + off) = v1 * v2;                                   \
    }                                                                      \
  }                                                                        \
} while (0)

__launch_bounds__(512, 2)
__global__ void conv_gemm(const float* __restrict__ x,
                          const _Float16* __restrict__ WE,
                          const _Float16* __restrict__ WO,
                          float* __restrict__ out,
                          float* __restrict__ stats) {
  extern __shared__ char smem[];
  float*    sstats = (float*)smem;                 // [128][2]
  _Float16* planes = (_Float16*)(smem + 1024);     // [2][PSZ]
  float*    abuf   = (float*)(smem + 1024);        // epilogue alias: [64][512]

  const int tile = blockIdx.x;        // 0..31
  const int b    = blockIdx.y;        // 0..15
  const int i0   = tile * NT;
  const int t    = threadIdx.x;
  const int lane = t & 63;
  const int wave = t >> 6;            // 0..7
  const int isO  = wave & 1;          // 0=even outputs, 1=odd outputs
  const int wn   = (wave >> 1) & 1;   // 128-col half of the tile
  const int wm   = wave >> 2;         // 64-cout half
  const int l15  = lane & 15, quad = lane >> 4;
  const int kl   = quad * 8;

  if (t < 128) { sstats[2 * t] = 0.f; sstats[2 * t + 1] = 0.f; }

  const float* xb = x + (size_t)b * CIN * LIN;
  const _Float16* Wsel = isO ? WO : WE;

  f32x4 acc[4][8];
  const f32x4 zero = {0.f, 0.f, 0.f, 0.f};
#pragma unroll
  for (int fm = 0; fm < 4; ++fm)
#pragma unroll
    for (int fn = 0; fn < 8; ++fn) acc[fm][fn] = zero;

  f16x8 af[2][4], bf[2][4];
  AFLOAD(af[0], 0);                 // weight prefetch: global, independent of barrier

  // ---- prologue: build P1 (x, fp16) only; P2/P3 derived later in-LDS ----
#pragma unroll
  for (int slot = 0; slot < 9; ++slot) {
    const bool tval = (slot < 8) || (t < PCOLS * 16 - 4096);   // 4128 tasks
    int task = t + 512 * slot;
    int g    = task / PCOLS;                        // 8-channel group 0..15
    int col  = task - g * PCOLS;                    // consecutive t -> consecutive col
    int gi   = i0 - 1 + col;
    const bool ok = tval && gi >= 0 && gi < LIN;
    const float* px = xb + (size_t)g * 8 * LIN + gi;
    f16x8 w1;
#pragma unroll
    for (int j = 0; j < 8; ++j) {
      float v = ok ? px[(size_t)j * LIN] : 0.f;
      w1[j] = (_Float16)v;
    }
    if (tval) *(f16x8*)(planes + col * PCPAD + g * 8) = w1;
  }
  __syncthreads();
  BFLOAD4(bf[0], planes, 0, 0);

#pragma unroll
  for (int q = 0; q < 3; ++q) {
    _Float16* cur = planes + ((q == 1) ? PSZ : 0);  // q0:P1(buf0) q1:P2(buf1) q2:P3(buf0)
#pragma unroll
    for (int s = 0; s < 8; ++s) {
      const int ks = q * 8 + s;
      // ---- half 0: prefetch af(ks+1) + bf half1, MFMA on bf[0] -> acc[.][0..3]
      if (ks + 1 < 24) AFLOAD(af[(ks + 1) & 1], ks + 1);
      BFLOAD4(bf[1], cur, s, 1);
      __builtin_amdgcn_s_setprio(1);
#pragma unroll
      for (int fm = 0; fm < 4; ++fm)
#pragma unroll
        for (int f4 = 0; f4 < 4; ++f4)
          acc[fm][f4] = __builtin_amdgcn_mfma_f32_16x16x32_f16(af[ks & 1][fm], bf[0][f4], acc[fm][f4], 0, 0, 0);
      __builtin_amdgcn_s_setprio(0);
      if (s == 0 && q == 0) BUILD_P2();   // buf1 <- P1*P1 (writes buf1; q0 reads buf0)
      if (s == 0 && q == 1) BUILD_P3();   // buf0 <- P2*P1 (writes buf0; q1 reads buf1)
      // ---- half 1: prefetch bf half0 of next s (same plane), MFMA -> acc[.][4..7]
      if (s < 7) BFLOAD4(bf[0], cur, s + 1, 0);
      __builtin_amdgcn_s_setprio(1);
#pragma unroll
      for (int fm = 0; fm < 4; ++fm)
#pragma unroll
        for (int f4 = 0; f4 < 4; ++f4)
          acc[fm][4 + f4] = __builtin_amdgcn_mfma_f32_16x16x32_f16(af[ks & 1][fm], bf[1][f4], acc[fm][4 + f4], 0, 0, 0);
      __builtin_amdgcn_s_setprio(0);
    }
    __syncthreads();   // derived plane complete/visible; cur safe for next q
    if (q < 2) BFLOAD4(bf[0], planes + ((q == 0) ? PSZ : 0), 0, 0);  // next plane, post-barrier
  }

  // --- stats: per-wave reduce + LDS atomics (C/D layout: n = lane&15, m = quad*4 + r) ---
#pragma unroll
  for (int fm = 0; fm < 4; ++fm) {
#pragma unroll
    for (int r = 0; r < 4; ++r) {
      float s1 = 0.f, s2 = 0.f;
#pragma unroll
      for (int fn = 0; fn < 8; ++fn) {
        float v = acc[fm][fn][r];
        s1 += v;
        s2 += v * v;
      }
#pragma unroll
      for (int off = 8; off >= 1; off >>= 1) {   // reduce across the 16 n-lanes
        s1 += __shfl_xor(s1, off, 64);
        s2 += __shfl_xor(s2, off, 64);
      }
      if (l15 == 0) {
        int co = wm * 64 + fm * 16 + quad * 4 + r;
        atomicAdd(&sstats[2 * co], s1);
        atomicAdd(&sstats[2 * co + 1], s2);
      }
    }
  }

  // --- epilogue: assemble 64-row halves in LDS, store contiguous full lines ---
#pragma unroll
  for (int pm = 0; pm < 2; ++pm) {
    __syncthreads();                  // abuf region free (planes dead / prev pass stored)
    if (wm == pm) {
#pragma unroll
      for (int fm = 0; fm < 4; ++fm)
#pragma unroll
        for (int r = 0; r < 4; ++r) {
          int lr = fm * 16 + quad * 4 + r;          // 0..63
#pragma unroll
          for (int fn = 0; fn < 8; ++fn) {
            int lc = wn * 128 + fn * 16 + l15;      // 0..255
            abuf[lr * 512 + 2 * lc + isO] = acc[fm][fn][r];
          }
        }
    }
    __syncthreads();
    float* dstbase = out + (size_t)b * COUT * LOUT + (size_t)(pm * 64) * LOUT + 2 * i0;
#pragma unroll
    for (int it = 0; it < 16; ++it) {               // 8192 f32x4 chunks / 512 thr
      int c  = t + it * 512;
      int cr = c >> 7, pos = c & 127;
      *(f32x4*)(dstbase + (size_t)cr * LOUT + pos * 4) = *(const f32x4*)(abuf + cr * 512 + pos * 4);
    }
  }
  if (t < 128) {
    atomicAdd(&stats[((size_t)b * COUT + t) * 2],     sstats[2 * t]);
    atomicAdd(&stats[((size_t)b * COUT + t) * 2 + 1], sstats[2 * t + 1]);
  }
}

// ---------------- instance norm + tanh, in place ----------------
__device__ inline float tanh_fast(float z) {
  float e = __expf(2.f * z);
  return 1.f - 2.f * __builtin_amdgcn_rcpf(e + 1.f);  // v_rcp_f32: no fdiv slow-path
}

__global__ void norm_tanh(float* __restrict__ out, const float* __restrict__ stats) {
  int row  = blockIdx.x >> 1;                   // b*128 + co
  int half = blockIdx.x & 1;
  float s1 = stats[2 * row], s2 = stats[2 * row + 1];
  const float invN = 1.f / (float)LOUT;
  float mean = s1 * invN;
  float var  = fmaxf(s2 * invN - mean * mean, 0.f);
  float inv  = rsqrtf(var + 1e-5f);
  float c0   = -mean * inv;
  float4* p = (float4*)(out + (size_t)row * LOUT) + half * (LOUT / 8);
  // 2048 float4 per half-row; 256 thr x 8 each; 4 loads in flight per thread
#pragma unroll
  for (int mi = 0; mi < 2; ++mi) {
    float4 v[4];
#pragma unroll
    for (int u = 0; u < 4; ++u) v[u] = p[threadIdx.x + 256 * (mi * 4 + u)];
#pragma unroll
    for (int u = 0; u < 4; ++u) {
      v[u].x = tanh_fast(fmaf(v[u].x, inv, c0));
      v[u].y = tanh_fast(fmaf(v[u].y, inv, c0));
      v[u].z = tanh_fast(fmaf(v[u].z, inv, c0));
      v[u].w = tanh_fast(fmaf(v[u].w, inv, c0));
    }
#pragma unroll
    for (int u = 0; u < 4; ++u) p[threadIdx.x + 256 * (mi * 4 + u)] = v[u];
  }
}

extern "C" void kernel_launch(void* const* d_in, const int* in_sizes, int n_in,
                              void* d_out, int out_size, void* d_ws, size_t ws_size,
                              hipStream_t stream) {
  const float* x = (const float*)d_in[0];
  const float* W = (const float*)d_in[1];
  // bias (d_in[2]) is exactly cancelled by InstanceNorm -> unused
  float* out = (float*)d_out;

  float*    stats = (float*)d_ws;
  _Float16* WE    = (_Float16*)((char*)d_ws + 16384);
  _Float16* WO    = WE + (size_t)COUT * KEXP;

  hipMemsetAsync(d_ws, 0, 16384, stream);
  prep_weights<<<dim3((COUT * KEXP) / 256), dim3(256), 0, stream>>>(W, WE, WO);

  size_t shmem = 1024 + (size_t)PSZ * 2 * 2;   // 141,376 B -> 1 block/CU, 8 waves
  hipFuncSetAttribute(reinterpret_cast<const void*>(conv_gemm),
                      hipFuncAttributeMaxDynamicSharedMemorySize, (int)shmem);
  conv_gemm<<<dim3(NTILES, BATCH), dim3(512), shmem, stream>>>(x, WE, WO, out, stats);

  norm_tanh<<<dim3(2 * BATCH * COUT), dim3(256), 0, stream>>>(out, stats);
}